// Round 10
// baseline (923.287 us; speedup 1.0000x reference)
//
#include <hip/hip_runtime.h>
#include <cstdint>
#include <cstddef>

#define DEV __device__ __forceinline__

static constexpr float QEPS = 1e-5f;   // reference EPS
static constexpr int   MTOK = 8192;    // B*S tokens
static constexpr int   EMB  = 2048;    // N_EMBD
static constexpr int   DFF  = 8192;    // 4*N_EMBD
static constexpr int   MCH  = 2048;    // M-chunk rows for fp32-H staging in d_out

typedef __attribute__((ext_vector_type(4))) int   i32x4;

// async 16B global->LDS (generic -> AS1/AS3 addrspace casts).
DEV void async_cp16(const void* g, void* l) {
  __builtin_amdgcn_global_load_lds(
      (const __attribute__((address_space(1))) void*)g,
      (__attribute__((address_space(3))) void*)l, 16, 0, 0);
}

// Raw barrier with compiler + machine-scheduler fences on both sides.
// __syncthreads() would emit s_waitcnt vmcnt(0) and kill the pipeline.
DEV void hard_barrier() {
  __builtin_amdgcn_sched_barrier(0);
  asm volatile("" ::: "memory");
  __builtin_amdgcn_s_barrier();
  asm volatile("" ::: "memory");
  __builtin_amdgcn_sched_barrier(0);
}

#define WAIT_VMCNT(N) do {                                   \
  __builtin_amdgcn_sched_barrier(0);                         \
  asm volatile("s_waitcnt vmcnt(" #N ")" ::: "memory");      \
  __builtin_amdgcn_sched_barrier(0);                         \
} while (0)

// Stage (PASSES*64) rows x 64B of i8 into LDS, 4-chunk XOR swizzle (round-8
// proven: 0 conflicts). Physical 16B chunk p of row r holds logical p^((r>>1)&3).
// gload_lds dest = wave base + lane*16 (linear, HW rule); swizzle on the
// per-lane GLOBAL source. 256 threads: wave w covers rows w*16+(l>>2) per pass.
template<int PASSES>
DEV void stage64(const signed char* __restrict__ g, size_t ldb,
                 signed char* lds, int tid) {
  const int w  = tid >> 6, l = tid & 63;
  const int rr = w * 16 + (l >> 2);
  const int p  = l & 3;                 // physical (dest) chunk
  const int q  = p ^ ((l >> 3) & 3);    // logical (source) chunk; (row>>1)&3==(l>>3)&3
#pragma unroll
  for (int it = 0; it < PASSES; ++it) {
    const int row = it * 64 + rr;
    async_cp16(g + (size_t)row * ldb + q * 16, lds + row * 64 + p * 16);
  }
}

// Swizzled fragment read: row r, fq selects the 16B K-chunk.
DEV i32x4 frag64(const signed char* lds, int row, int fq) {
  const int ch = (fq ^ ((row >> 1) & 3)) << 4;
  return *(const i32x4*)&lds[row * 64 + ch];
}

DEV float block_sum(float v) {
#pragma unroll
  for (int off = 32; off > 0; off >>= 1) v += __shfl_down(v, off);
  __shared__ float b[4];
  if ((threadIdx.x & 63) == 0) b[threadIdx.x >> 6] = v;
  __syncthreads();
  return (b[0] + b[1]) + (b[2] + b[3]);
}

DEV float block_max(float v) {
#pragma unroll
  for (int off = 32; off > 0; off >>= 1) v = fmaxf(v, __shfl_down(v, off));
  __shared__ float b[4];
  if ((threadIdx.x & 63) == 0) b[threadIdx.x >> 6] = v;
  __syncthreads();
  return fmaxf(fmaxf(b[0], b[1]), fmaxf(b[2], b[3]));
}

// ---------------- accurate fp32 pairwise-style sum of |w|, n = 2^24 ----------
__global__ __launch_bounds__(256) void np_absmean_stage1(
    const float* __restrict__ w, float* __restrict__ partials) {
  const int t = threadIdx.x;
  const size_t leaf = (size_t)blockIdx.x * 256 + t;
  const float4* a4 = (const float4*)(w + leaf * 128);
  float L[16];
#pragma unroll
  for (int q = 0; q < 4; ++q) {
    float4 v0 = a4[q +  0];
    float4 v1 = a4[q +  4];
    float4 v2 = a4[q +  8];
    float4 v3 = a4[q + 12];
    float4 v4 = a4[q + 16];
    float4 v5 = a4[q + 20];
    float4 v6 = a4[q + 24];
    float4 v7 = a4[q + 28];
    L[4*q+0] = ((fabsf(v0.x)+fabsf(v1.x)) + (fabsf(v2.x)+fabsf(v3.x)))
             + ((fabsf(v4.x)+fabsf(v5.x)) + (fabsf(v6.x)+fabsf(v7.x)));
    L[4*q+1] = ((fabsf(v0.y)+fabsf(v1.y)) + (fabsf(v2.y)+fabsf(v3.y)))
             + ((fabsf(v4.y)+fabsf(v5.y)) + (fabsf(v6.y)+fabsf(v7.y)));
    L[4*q+2] = ((fabsf(v0.z)+fabsf(v1.z)) + (fabsf(v2.z)+fabsf(v3.z)))
             + ((fabsf(v4.z)+fabsf(v5.z)) + (fabsf(v6.z)+fabsf(v7.z)));
    L[4*q+3] = ((fabsf(v0.w)+fabsf(v1.w)) + (fabsf(v2.w)+fabsf(v3.w)))
             + ((fabsf(v4.w)+fabsf(v5.w)) + (fabsf(v6.w)+fabsf(v7.w)));
  }
#pragma unroll
  for (int l = 0; l < 8; ++l) L[l] += L[l + 8];
#pragma unroll
  for (int l = 0; l < 4; ++l) L[l] += L[l + 4];
  L[0] += L[2]; L[1] += L[3];
  const float res = L[0] + L[1];

  __shared__ float s[256];
  s[t] = res;
  __syncthreads();
  for (int width = 256; width > 1; width >>= 1) {
    const int half = width >> 1;
    float v = 0.f;
    if (t < half) v = s[2 * t] + s[2 * t + 1];
    __syncthreads();
    if (t < half) s[t] = v;
    __syncthreads();
  }
  if (t == 0) partials[blockIdx.x] = s[0];
}

__global__ __launch_bounds__(256) void np_absmean_stage2(
    const float* __restrict__ partials, float* __restrict__ out) {
  const int t = threadIdx.x;
  __shared__ float s[512];
  s[t] = partials[t];
  s[t + 256] = partials[t + 256];
  __syncthreads();
  for (int width = 512; width > 1; width >>= 1) {
    const int half = width >> 1;
    float v = 0.f;
    if (t < half) v = s[2 * t] + s[2 * t + 1];
    __syncthreads();
    if (t < half) s[t] = v;
    __syncthreads();
  }
  if (t == 0) out[0] = s[0];
}

// ---------------- ternary weight quant w/ boundary hedge -> int8 {0,±1,±2} ---
__global__ __launch_bounds__(256) void quant_w_kernel(
    const float* __restrict__ w, signed char* __restrict__ wq,
    const float* __restrict__ sumf, size_t n4) {
  const double mean = (double)(*sumf) * (1.0 / 16777216.0);   // /2^24 exact
  const double sc   = 1.0 / fmax(mean, (double)QEPS);
  const float4* w4 = (const float4*)w;
  int* o4 = (int*)wq;
  const size_t stride = (size_t)gridDim.x * blockDim.x;
  for (size_t i = (size_t)blockIdx.x * blockDim.x + threadIdx.x; i < n4; i += stride) {
    float4 v = w4[i];
    union { int i4; signed char c[4]; } p;
#pragma unroll
    for (int j = 0; j < 4; ++j) {
      const double pd = (double)(&v.x)[j] * sc;
      double r = fmin(fmax(rint(pd), -1.0), 1.0);
      if (fabs(fabs(pd) - 0.5) < 2e-7) r = (pd > 0.0) ? 0.5 : -0.5;
      p.c[j] = (signed char)(int)(2.0 * r);
    }
    o4[i] = p.i4;
  }
}

// ---------------- rmsnorm + absmax-quant of x rows (2048) -> int8 + scale ----
__global__ __launch_bounds__(256) void rms_quant_x_kernel(
    const float* __restrict__ x, signed char* __restrict__ xq,
    float* __restrict__ s_out) {
  const size_t row = blockIdx.x;
  const float* xr = x + row * EMB;
  const int t = threadIdx.x;
  float4 v0 = ((const float4*)xr)[t];
  float4 v1 = ((const float4*)xr)[t + 256];
  float vals[8] = {v0.x, v0.y, v0.z, v0.w, v1.x, v1.y, v1.z, v1.w};
  float ss = 0.f;
#pragma unroll
  for (int i = 0; i < 8; ++i) ss += vals[i] * vals[i];
  ss = block_sum(ss);
  const float r = 1.0f / sqrtf(ss * (1.0f / (float)EMB) + 1e-6f);
  float xn[8], am = 0.f;
#pragma unroll
  for (int i = 0; i < 8; ++i) { xn[i] = vals[i] * r; am = fmaxf(am, fabsf(xn[i])); }
  am = block_max(am);
  const float s = 127.0f / fmaxf(am, QEPS);
  union { int i; signed char c[4]; } p0, p1;
#pragma unroll
  for (int i = 0; i < 4; ++i) {
    p0.c[i] = (signed char)(int)fminf(fmaxf(rintf(xn[i]     * s), -128.f), 127.f);
    p1.c[i] = (signed char)(int)fminf(fmaxf(rintf(xn[4 + i] * s), -128.f), 127.f);
  }
  int* qr = (int*)(xq + row * EMB);
  qr[t]       = p0.i;
  qr[t + 256] = p1.i;
  if (t == 0) s_out[row] = s;
}

// ---------------- rmsnorm + absmax-quant of fp32 H rows (8192) -> int8 + scale
__global__ __launch_bounds__(256) void rms_quant_h_kernel(
    const float* __restrict__ H, signed char* __restrict__ hq,
    float* __restrict__ s_out) {
  const size_t row = blockIdx.x;
  const float* hr = H + row * (size_t)DFF;
  const int t = threadIdx.x;
  float vals[32];
#pragma unroll
  for (int k = 0; k < 8; ++k) {
    float4 v = ((const float4*)hr)[t + k * 256];
    vals[k * 4 + 0] = v.x; vals[k * 4 + 1] = v.y;
    vals[k * 4 + 2] = v.z; vals[k * 4 + 3] = v.w;
  }
  float ss = 0.f;
#pragma unroll
  for (int i = 0; i < 32; ++i) ss += vals[i] * vals[i];
  ss = block_sum(ss);
  const float r = 1.0f / sqrtf(ss * (1.0f / (float)DFF) + 1e-6f);
  float am = 0.f;
#pragma unroll
  for (int i = 0; i < 32; ++i) { vals[i] *= r; am = fmaxf(am, fabsf(vals[i])); }
  am = block_max(am);
  const float s = 127.0f / fmaxf(am, QEPS);
  int* qrow = (int*)(hq + row * (size_t)DFF);
#pragma unroll
  for (int k = 0; k < 8; ++k) {
    union { int i; signed char c[4]; } p;
#pragma unroll
    for (int j = 0; j < 4; ++j) {
      float q = fminf(fmaxf(rintf(vals[k * 4 + j] * s), -128.f), 127.f);
      p.c[j] = (signed char)(int)q;
    }
    qrow[t + k * 256] = p.i;
  }
  if (t == 0) s_out[row] = s;
}

// ---------------- dual GEMM i8, 128x128 tile, BK=64, dbuf + counted vmcnt ----
// 256 thr / 4 waves (2Mx2N), wave 64x64 per GEMM. LDS 2x(3x8K) = 48 KiB,
// regs ~228/wave -> 2 blocks/CU: one wave per block per SIMD, so block A's
// epilogue (64 expf + 64 div / thread) overlaps block B's MFMA loop.
__global__ __launch_bounds__(256, 2) void dual_gemm_silu_kernel(
    const signed char* __restrict__ Xq, const signed char* __restrict__ W1,
    const signed char* __restrict__ W2, float* __restrict__ H,
    const float* __restrict__ s_x, const float* __restrict__ wsum) {
  __shared__ alignas(16) signed char sA [2][128 * 64];
  __shared__ alignas(16) signed char sB1[2][128 * 64];
  __shared__ alignas(16) signed char sB2[2][128 * 64];
  const int tid = threadIdx.x;
  const int lane = tid & 63, wv = tid >> 6;
  const int wm = (wv >> 1) * 64, wn = (wv & 1) * 64;
  // XCD swizzle: grid (64, 16) = 1024 blocks, 128/XCD
  const int gx = gridDim.x;
  int lid = blockIdx.y * gx + blockIdx.x;
  const int cpx = (gx * gridDim.y) >> 3;
  lid = (lid & 7) * cpx + (lid >> 3);
  const int bm = (lid / gx) * 128, bn = (lid % gx) * 128;
  const int fr = lane & 15, fq = lane >> 4;

  i32x4 acc1[4][4] = {}, acc2[4][4] = {};

  stage64<2>(Xq + (size_t)bm * EMB, EMB, sA[0],  tid);
  stage64<2>(W1 + (size_t)bn * EMB, EMB, sB1[0], tid);
  stage64<2>(W2 + (size_t)bn * EMB, EMB, sB2[0], tid);

  constexpr int NKT = EMB / 64;   // 32
  int c = 0;
  for (int kt = 0; kt < NKT; ++kt) {
    if (kt + 1 < NKT) {
      const int ko = (kt + 1) * 64;
      stage64<2>(Xq + (size_t)bm * EMB + ko, EMB, sA[c ^ 1],  tid);
      stage64<2>(W1 + (size_t)bn * EMB + ko, EMB, sB1[c ^ 1], tid);
      stage64<2>(W2 + (size_t)bn * EMB + ko, EMB, sB2[c ^ 1], tid);
      WAIT_VMCNT(6);      // the 6 just-issued may fly; kt's 6 have landed
    } else {
      WAIT_VMCNT(0);
    }
    hard_barrier();
    const signed char* a  = sA[c];
    const signed char* b1 = sB1[c];
    const signed char* b2 = sB2[c];
    i32x4 af[4], f1[4], f2[4];
#pragma unroll
    for (int i = 0; i < 4; ++i) af[i] = frag64(a,  wm + i * 16 + fr, fq);
#pragma unroll
    for (int j = 0; j < 4; ++j) {
      f1[j] = frag64(b1, wn + j * 16 + fr, fq);
      f2[j] = frag64(b2, wn + j * 16 + fr, fq);
    }
    __builtin_amdgcn_s_setprio(1);
#pragma unroll
    for (int i = 0; i < 4; ++i)
#pragma unroll
      for (int j = 0; j < 4; ++j) {
        acc1[i][j] = __builtin_amdgcn_mfma_i32_16x16x64_i8(af[i], f1[j], acc1[i][j], 0, 0, 0);
        acc2[i][j] = __builtin_amdgcn_mfma_i32_16x16x64_i8(af[i], f2[j], acc2[i][j], 0, 0, 0);
      }
    __builtin_amdgcn_s_setprio(0);
    hard_barrier();       // all waves done reading buf c -> next STAGE may overwrite
    c ^= 1;
  }

  const float sw1 = 1.0f / fmaxf(wsum[0] * (1.0f / 16777216.0f), QEPS);
  const float sw2 = 1.0f / fmaxf(wsum[1] * (1.0f / 16777216.0f), QEPS);
#pragma unroll
  for (int i = 0; i < 4; ++i) {
#pragma unroll
    for (int r = 0; r < 4; ++r) {
      const int m = bm + wm + i * 16 + fq * 4 + r;
      const float d1 = s_x[m] * sw1;
      const float d2 = s_x[m] * sw2;
#pragma unroll
      for (int j = 0; j < 4; ++j) {
        const float t1 = ((float)acc1[i][j][r] * 0.5f) / d1;
        const float t2 = ((float)acc2[i][j][r] * 0.5f) / d2;
        const float hv = (t1 / (1.0f + expf(-t1))) * t2;
        H[(size_t)m * DFF + (bn + wn + j * 16 + fr)] = hv;
      }
    }
  }
}

// ---------------- GEMM3 i8, 256x128 tile, BK=64, dbuf + counted vmcnt --------
// 256 thr / 4 waves (2Mx2N), wave 128x64. LDS 2x(16K+8K) = 48 KiB ->
// 2 blocks/CU (grid 512 = exactly one co-resident generation).
__global__ __launch_bounds__(256, 2) void gemm_out_kernel(
    const signed char* __restrict__ Aq, const signed char* __restrict__ B,
    float* __restrict__ C, const float* __restrict__ s_a,
    const float* __restrict__ wsum2) {
  __shared__ alignas(16) signed char sA[2][256 * 64];
  __shared__ alignas(16) signed char sB[2][128 * 64];
  const int tid = threadIdx.x;
  const int lane = tid & 63, wv = tid >> 6;
  const int wm = (wv >> 1) * 128, wn = (wv & 1) * 64;
  // XCD swizzle: grid (16, 32) = 512 blocks, 64/XCD
  const int gx = gridDim.x;
  int lid = blockIdx.y * gx + blockIdx.x;
  const int cpx = (gx * gridDim.y) >> 3;
  lid = (lid & 7) * cpx + (lid >> 3);
  const int bm = (lid / gx) * 256, bn = (lid % gx) * 128;
  const int fr = lane & 15, fq = lane >> 4;

  i32x4 acc[8][4] = {};

  stage64<4>(Aq + (size_t)bm * DFF, DFF, sA[0], tid);
  stage64<2>(B  + (size_t)bn * DFF, DFF, sB[0], tid);

  constexpr int NKT = DFF / 64;   // 128
  int c = 0;
  for (int kt = 0; kt < NKT; ++kt) {
    if (kt + 1 < NKT) {
      const int ko = (kt + 1) * 64;
      stage64<4>(Aq + (size_t)bm * DFF + ko, DFF, sA[c ^ 1], tid);
      stage64<2>(B  + (size_t)bn * DFF + ko, DFF, sB[c ^ 1], tid);
      WAIT_VMCNT(6);
    } else {
      WAIT_VMCNT(0);
    }
    hard_barrier();
    const signed char* a = sA[c];
    const signed char* b = sB[c];
    i32x4 af[8], bf[4];
#pragma unroll
    for (int i = 0; i < 8; ++i) af[i] = frag64(a, wm + i * 16 + fr, fq);
#pragma unroll
    for (int j = 0; j < 4; ++j) bf[j] = frag64(b, wn + j * 16 + fr, fq);
    __builtin_amdgcn_s_setprio(1);
#pragma unroll
    for (int i = 0; i < 8; ++i)
#pragma unroll
      for (int j = 0; j < 4; ++j)
        acc[i][j] = __builtin_amdgcn_mfma_i32_16x16x64_i8(af[i], bf[j], acc[i][j], 0, 0, 0);
    __builtin_amdgcn_s_setprio(0);
    hard_barrier();
    c ^= 1;
  }

  const float sw = 1.0f / fmaxf(wsum2[0] * (1.0f / 16777216.0f), QEPS);
#pragma unroll
  for (int i = 0; i < 8; ++i) {
#pragma unroll
    for (int r = 0; r < 4; ++r) {
      const int m = bm + wm + i * 16 + fq * 4 + r;
      const float d = s_a[m] * sw;
#pragma unroll
      for (int j = 0; j < 4; ++j)
        C[(size_t)m * EMB + (bn + wn + j * 16 + fr)] = ((float)acc[i][j][r] * 0.5f) / d;
    }
  }
}

extern "C" void kernel_launch(void* const* d_in, const int* in_sizes, int n_in,
                              void* d_out, int out_size, void* d_ws, size_t ws_size,
                              hipStream_t stream) {
  const float* x  = (const float*)d_in[0];
  const float* w1 = (const float*)d_in[1];
  const float* w2 = (const float*)d_in[2];
  const float* w3 = (const float*)d_in[3];
  float* out = (float*)d_out;

  const size_t NW = (size_t)DFF * EMB;       // 2^24 elems per weight
  const size_t MB = 1ull << 20;

  char* ws = (char*)d_ws;
  float* wsum = (float*)ws;                  // 3 accurate fp32 sums
  float* s_x  = (float*)(ws + 4096);         // 8192 floats
  float* s_h  = (float*)(ws + 4096 + 32768); // 8192 floats
  float* parts = (float*)(ws + 128 * 1024);  // 3 x 512 floats
  signed char* xq  = (signed char*)(ws + MB);
  signed char* wq1 = (signed char*)(ws + 33 * MB);
  signed char* wq3 = wq1;                    // overlay (wq1 dead after dual GEMM)
  signed char* wq2 = (signed char*)(ws + 65 * MB);
  signed char* hq  = (signed char*)(ws + 97 * MB);
  float* H = (float*)d_out;                  // fp32 H chunk buffer

  np_absmean_stage1<<<512, 256, 0, stream>>>(w1, parts);
  np_absmean_stage2<<<1, 256, 0, stream>>>(parts, wsum + 0);
  np_absmean_stage1<<<512, 256, 0, stream>>>(w2, parts + 512);
  np_absmean_stage2<<<1, 256, 0, stream>>>(parts + 512, wsum + 1);
  np_absmean_stage1<<<512, 256, 0, stream>>>(w3, parts + 1024);
  np_absmean_stage2<<<1, 256, 0, stream>>>(parts + 1024, wsum + 2);
  quant_w_kernel<<<1024, 256, 0, stream>>>(w1, wq1, wsum + 0, NW / 4);
  quant_w_kernel<<<1024, 256, 0, stream>>>(w2, wq2, wsum + 1, NW / 4);
  rms_quant_x_kernel<<<MTOK, 256, 0, stream>>>(x, xq, s_x);

  for (int c = 0; c < MTOK / MCH; ++c) {
    dual_gemm_silu_kernel<<<dim3(DFF / 128, MCH / 128), 256, 0, stream>>>(
        xq + (size_t)c * MCH * EMB, wq1, wq2, H, s_x + c * MCH, wsum);
    rms_quant_h_kernel<<<MCH, 256, 0, stream>>>(
        H, hq + (size_t)c * MCH * DFF, s_h + c * MCH);
  }

  quant_w_kernel<<<1024, 256, 0, stream>>>(w3, wq3, wsum + 2, NW / 4);
  gemm_out_kernel<<<dim3(EMB / 128, MTOK / 256), 256, 0, stream>>>(
      hq, wq3, out, s_h, wsum + 2);
}

// Round 11
// 804.250 us; speedup vs baseline: 1.1480x; 1.1480x over previous
//
#include <hip/hip_runtime.h>
#include <cstdint>
#include <cstddef>

#define DEV __device__ __forceinline__

static constexpr float QEPS = 1e-5f;   // reference EPS
static constexpr int   MTOK = 8192;    // B*S tokens
static constexpr int   EMB  = 2048;    // N_EMBD
static constexpr int   DFF  = 8192;    // 4*N_EMBD
static constexpr int   MCH  = 2048;    // M-chunk rows for fp32-H staging in d_out

typedef __attribute__((ext_vector_type(4))) int   i32x4;

// async 16B global->LDS (generic -> AS1/AS3 addrspace casts).
DEV void async_cp16(const void* g, void* l) {
  __builtin_amdgcn_global_load_lds(
      (const __attribute__((address_space(1))) void*)g,
      (__attribute__((address_space(3))) void*)l, 16, 0, 0);
}

// Raw barrier with compiler + machine-scheduler fences on both sides
// (gemm_out deep pipeline only; __syncthreads would drain vmcnt to 0).
DEV void hard_barrier() {
  __builtin_amdgcn_sched_barrier(0);
  asm volatile("" ::: "memory");
  __builtin_amdgcn_s_barrier();
  asm volatile("" ::: "memory");
  __builtin_amdgcn_sched_barrier(0);
}

#define WAIT_VMCNT(N) do {                                   \
  __builtin_amdgcn_sched_barrier(0);                         \
  asm volatile("s_waitcnt vmcnt(" #N ")" ::: "memory");      \
  __builtin_amdgcn_sched_barrier(0);                         \
} while (0)

// ---- round-8 proven staging: 128 rows x 64B, 4-chunk XOR swizzle (0 confl) --
// physical 16B chunk p of row r holds logical p ^ ((r>>1)&3); dest linear
// (gload_lds HW rule), swizzle on per-lane global source. 256-thread blocks.
DEV void stage_tile64(const signed char* __restrict__ g, size_t ldb,
                      signed char* lds, int tid) {
  const int w  = tid >> 6, l = tid & 63;
  const int rr = w * 16 + (l >> 2);
  const int p  = l & 3;
  const int q  = p ^ ((l >> 3) & 3);
#pragma unroll
  for (int it = 0; it < 2; ++it) {
    const int r = it * 64 + rr;
    async_cp16(g + (size_t)r * ldb + q * 16, lds + r * 64 + p * 16);
  }
}

// ---- round-9 proven staging: (PASSES*64) rows x 128B, 8-chunk XOR swizzle ---
template<int PASSES>
DEV void stage128(const signed char* __restrict__ g, size_t ldb,
                  signed char* lds, int tid) {
  const int w  = tid >> 6, l = tid & 63;
  const int r8 = l >> 3;
  const int p  = l & 7;
  const int q  = p ^ r8;
#pragma unroll
  for (int it = 0; it < PASSES; ++it) {
    const int row = it * 64 + w * 8 + r8;
    async_cp16(g + (size_t)row * ldb + q * 16, lds + row * 128 + p * 16);
  }
}

// Swizzled fragment read for the 128B-row layout.
DEV i32x4 lds_frag(const signed char* lds, int row, int s, int fq) {
  const int ch = ((s * 4 + fq) ^ (row & 7)) * 16;
  return *(const i32x4*)&lds[row * 128 + ch];
}

DEV float block_sum(float v) {
#pragma unroll
  for (int off = 32; off > 0; off >>= 1) v += __shfl_down(v, off);
  __shared__ float b[4];
  if ((threadIdx.x & 63) == 0) b[threadIdx.x >> 6] = v;
  __syncthreads();
  return (b[0] + b[1]) + (b[2] + b[3]);
}

DEV float block_max(float v) {
#pragma unroll
  for (int off = 32; off > 0; off >>= 1) v = fmaxf(v, __shfl_down(v, off));
  __shared__ float b[4];
  if ((threadIdx.x & 63) == 0) b[threadIdx.x >> 6] = v;
  __syncthreads();
  return fmaxf(fmaxf(b[0], b[1]), fmaxf(b[2], b[3]));
}

// ---------------- accurate fp32 pairwise-style sum of |w|, n = 2^24 ----------
__global__ __launch_bounds__(256) void np_absmean_stage1(
    const float* __restrict__ w, float* __restrict__ partials) {
  const int t = threadIdx.x;
  const size_t leaf = (size_t)blockIdx.x * 256 + t;
  const float4* a4 = (const float4*)(w + leaf * 128);
  float L[16];
#pragma unroll
  for (int q = 0; q < 4; ++q) {
    float4 v0 = a4[q +  0];
    float4 v1 = a4[q +  4];
    float4 v2 = a4[q +  8];
    float4 v3 = a4[q + 12];
    float4 v4 = a4[q + 16];
    float4 v5 = a4[q + 20];
    float4 v6 = a4[q + 24];
    float4 v7 = a4[q + 28];
    L[4*q+0] = ((fabsf(v0.x)+fabsf(v1.x)) + (fabsf(v2.x)+fabsf(v3.x)))
             + ((fabsf(v4.x)+fabsf(v5.x)) + (fabsf(v6.x)+fabsf(v7.x)));
    L[4*q+1] = ((fabsf(v0.y)+fabsf(v1.y)) + (fabsf(v2.y)+fabsf(v3.y)))
             + ((fabsf(v4.y)+fabsf(v5.y)) + (fabsf(v6.y)+fabsf(v7.y)));
    L[4*q+2] = ((fabsf(v0.z)+fabsf(v1.z)) + (fabsf(v2.z)+fabsf(v3.z)))
             + ((fabsf(v4.z)+fabsf(v5.z)) + (fabsf(v6.z)+fabsf(v7.z)));
    L[4*q+3] = ((fabsf(v0.w)+fabsf(v1.w)) + (fabsf(v2.w)+fabsf(v3.w)))
             + ((fabsf(v4.w)+fabsf(v5.w)) + (fabsf(v6.w)+fabsf(v7.w)));
  }
#pragma unroll
  for (int l = 0; l < 8; ++l) L[l] += L[l + 8];
#pragma unroll
  for (int l = 0; l < 4; ++l) L[l] += L[l + 4];
  L[0] += L[2]; L[1] += L[3];
  const float res = L[0] + L[1];

  __shared__ float s[256];
  s[t] = res;
  __syncthreads();
  for (int width = 256; width > 1; width >>= 1) {
    const int half = width >> 1;
    float v = 0.f;
    if (t < half) v = s[2 * t] + s[2 * t + 1];
    __syncthreads();
    if (t < half) s[t] = v;
    __syncthreads();
  }
  if (t == 0) partials[blockIdx.x] = s[0];
}

__global__ __launch_bounds__(256) void np_absmean_stage2(
    const float* __restrict__ partials, float* __restrict__ out) {
  const int t = threadIdx.x;
  __shared__ float s[512];
  s[t] = partials[t];
  s[t + 256] = partials[t + 256];
  __syncthreads();
  for (int width = 512; width > 1; width >>= 1) {
    const int half = width >> 1;
    float v = 0.f;
    if (t < half) v = s[2 * t] + s[2 * t + 1];
    __syncthreads();
    if (t < half) s[t] = v;
    __syncthreads();
  }
  if (t == 0) out[0] = s[0];
}

// ---------------- ternary weight quant w/ boundary hedge -> int8 {0,±1,±2} ---
__global__ __launch_bounds__(256) void quant_w_kernel(
    const float* __restrict__ w, signed char* __restrict__ wq,
    const float* __restrict__ sumf, size_t n4) {
  const double mean = (double)(*sumf) * (1.0 / 16777216.0);   // /2^24 exact
  const double sc   = 1.0 / fmax(mean, (double)QEPS);
  const float4* w4 = (const float4*)w;
  int* o4 = (int*)wq;
  const size_t stride = (size_t)gridDim.x * blockDim.x;
  for (size_t i = (size_t)blockIdx.x * blockDim.x + threadIdx.x; i < n4; i += stride) {
    float4 v = w4[i];
    union { int i4; signed char c[4]; } p;
#pragma unroll
    for (int j = 0; j < 4; ++j) {
      const double pd = (double)(&v.x)[j] * sc;
      double r = fmin(fmax(rint(pd), -1.0), 1.0);
      if (fabs(fabs(pd) - 0.5) < 2e-7) r = (pd > 0.0) ? 0.5 : -0.5;
      p.c[j] = (signed char)(int)(2.0 * r);
    }
    o4[i] = p.i4;
  }
}

// ---------------- rmsnorm + absmax-quant of x rows (2048) -> int8 + scale ----
__global__ __launch_bounds__(256) void rms_quant_x_kernel(
    const float* __restrict__ x, signed char* __restrict__ xq,
    float* __restrict__ s_out) {
  const size_t row = blockIdx.x;
  const float* xr = x + row * EMB;
  const int t = threadIdx.x;
  float4 v0 = ((const float4*)xr)[t];
  float4 v1 = ((const float4*)xr)[t + 256];
  float vals[8] = {v0.x, v0.y, v0.z, v0.w, v1.x, v1.y, v1.z, v1.w};
  float ss = 0.f;
#pragma unroll
  for (int i = 0; i < 8; ++i) ss += vals[i] * vals[i];
  ss = block_sum(ss);
  const float r = 1.0f / sqrtf(ss * (1.0f / (float)EMB) + 1e-6f);
  float xn[8], am = 0.f;
#pragma unroll
  for (int i = 0; i < 8; ++i) { xn[i] = vals[i] * r; am = fmaxf(am, fabsf(xn[i])); }
  am = block_max(am);
  const float s = 127.0f / fmaxf(am, QEPS);
  union { int i; signed char c[4]; } p0, p1;
#pragma unroll
  for (int i = 0; i < 4; ++i) {
    p0.c[i] = (signed char)(int)fminf(fmaxf(rintf(xn[i]     * s), -128.f), 127.f);
    p1.c[i] = (signed char)(int)fminf(fmaxf(rintf(xn[4 + i] * s), -128.f), 127.f);
  }
  int* qr = (int*)(xq + row * EMB);
  qr[t]       = p0.i;
  qr[t + 256] = p1.i;
  if (t == 0) s_out[row] = s;
}

// ---------------- rmsnorm + absmax-quant of fp32 H rows (8192) -> int8 + scale
__global__ __launch_bounds__(256) void rms_quant_h_kernel(
    const float* __restrict__ H, signed char* __restrict__ hq,
    float* __restrict__ s_out) {
  const size_t row = blockIdx.x;
  const float* hr = H + row * (size_t)DFF;
  const int t = threadIdx.x;
  float vals[32];
#pragma unroll
  for (int k = 0; k < 8; ++k) {
    float4 v = ((const float4*)hr)[t + k * 256];
    vals[k * 4 + 0] = v.x; vals[k * 4 + 1] = v.y;
    vals[k * 4 + 2] = v.z; vals[k * 4 + 3] = v.w;
  }
  float ss = 0.f;
#pragma unroll
  for (int i = 0; i < 32; ++i) ss += vals[i] * vals[i];
  ss = block_sum(ss);
  const float r = 1.0f / sqrtf(ss * (1.0f / (float)DFF) + 1e-6f);
  float am = 0.f;
#pragma unroll
  for (int i = 0; i < 32; ++i) { vals[i] *= r; am = fmaxf(am, fabsf(vals[i])); }
  am = block_max(am);
  const float s = 127.0f / fmaxf(am, QEPS);
  int* qrow = (int*)(hq + row * (size_t)DFF);
#pragma unroll
  for (int k = 0; k < 8; ++k) {
    union { int i; signed char c[4]; } p;
#pragma unroll
    for (int j = 0; j < 4; ++j) {
      float q = fminf(fmaxf(rintf(vals[k * 4 + j] * s), -128.f), 127.f);
      p.c[j] = (signed char)(int)q;
    }
    qrow[t + k * 256] = p.i;
  }
  if (t == 0) s_out[row] = s;
}

// ---------------- dual GEMM i8 (round-8 structure, fast epilogue) ------------
// 128x128 tile, BK=64, single-buffered 2-barrier loop, 256 thr / 4 waves.
// Epilogue: per-row folded reciprocals (32 IEEE div total) + native exp/rcp
// silu — cuts ~2800 VALU instr to ~500 (epilogue was ~40% of dual's time).
__global__ __launch_bounds__(256, 2) void dual_gemm_silu_kernel(
    const signed char* __restrict__ Xq, const signed char* __restrict__ W1,
    const signed char* __restrict__ W2, float* __restrict__ H,
    const float* __restrict__ s_x, const float* __restrict__ wsum) {
  __shared__ alignas(16) signed char sA [128 * 64];
  __shared__ alignas(16) signed char sB1[128 * 64];
  __shared__ alignas(16) signed char sB2[128 * 64];
  const int tid = threadIdx.x;
  const int lane = tid & 63, wv = tid >> 6;
  const int wm = (wv >> 1) * 64, wn = (wv & 1) * 64;
  const int bm = blockIdx.y * 128, bn = blockIdx.x * 128;
  const int fr = lane & 15, fq = lane >> 4;
  const int ch = (fq ^ ((fr >> 1) & 3)) * 16;   // swizzled read chunk (bytes)

  i32x4 acc1[4][4] = {}, acc2[4][4] = {};

  for (int k0 = 0; k0 < EMB; k0 += 64) {
    stage_tile64(Xq + (size_t)bm * EMB + k0, EMB, sA,  tid);
    stage_tile64(W1 + (size_t)bn * EMB + k0, EMB, sB1, tid);
    stage_tile64(W2 + (size_t)bn * EMB + k0, EMB, sB2, tid);
    __syncthreads();
    i32x4 af[4], f1[4], f2[4];
#pragma unroll
    for (int i = 0; i < 4; ++i)
      af[i] = *(const i32x4*)&sA[(wm + i * 16 + fr) * 64 + ch];
#pragma unroll
    for (int j = 0; j < 4; ++j) {
      f1[j] = *(const i32x4*)&sB1[(wn + j * 16 + fr) * 64 + ch];
      f2[j] = *(const i32x4*)&sB2[(wn + j * 16 + fr) * 64 + ch];
    }
#pragma unroll
    for (int i = 0; i < 4; ++i)
#pragma unroll
      for (int j = 0; j < 4; ++j) {
        acc1[i][j] = __builtin_amdgcn_mfma_i32_16x16x64_i8(af[i], f1[j], acc1[i][j], 0, 0, 0);
        acc2[i][j] = __builtin_amdgcn_mfma_i32_16x16x64_i8(af[i], f2[j], acc2[i][j], 0, 0, 0);
      }
    __syncthreads();
  }

  const float sw1 = 1.0f / fmaxf(wsum[0] * (1.0f / 16777216.0f), QEPS);
  const float sw2 = 1.0f / fmaxf(wsum[1] * (1.0f / 16777216.0f), QEPS);
#pragma unroll
  for (int i = 0; i < 4; ++i) {
#pragma unroll
    for (int r = 0; r < 4; ++r) {
      const int m = bm + wm + i * 16 + fq * 4 + r;
      const float id1 = 0.5f / (s_x[m] * sw1);    // one div per row
      const float id2 = 0.5f / (s_x[m] * sw2);
#pragma unroll
      for (int j = 0; j < 4; ++j) {
        const float t1 = (float)acc1[i][j][r] * id1;
        const float t2 = (float)acc2[i][j][r] * id2;
        const float sig = __builtin_amdgcn_rcpf(1.0f + __expf(-t1));
        H[(size_t)m * DFF + (bn + wn + j * 16 + fr)] = t1 * sig * t2;
      }
    }
  }
}

// ---------------- GEMM3 i8 (round-9 deep pipeline, fast epilogue) ------------
// 256x256 tile, BK=128, dbuf + counted vmcnt + raw barriers, 512 thr / 8 waves.
__global__ __launch_bounds__(512, 1) void gemm_out_kernel(
    const signed char* __restrict__ Aq, const signed char* __restrict__ B,
    float* __restrict__ C, const float* __restrict__ s_a,
    const float* __restrict__ wsum2) {
  __shared__ alignas(16) signed char sA[2][256 * 128];
  __shared__ alignas(16) signed char sB[2][256 * 128];
  const int tid = threadIdx.x;
  const int lane = tid & 63, wv = tid >> 6;
  const int wm = (wv >> 2) * 128, wn = (wv & 3) * 64;
  // XCD swizzle: grid (8, 32) = 256 blocks, 32/XCD
  const int gx = gridDim.x;
  int lid = blockIdx.y * gx + blockIdx.x;
  const int cpx = (gx * gridDim.y) >> 3;
  lid = (lid & 7) * cpx + (lid >> 3);
  const int bm = (lid / gx) * 256, bn = (lid % gx) * 256;
  const int fr = lane & 15, fq = lane >> 4;

  i32x4 acc[8][4] = {};

  stage128<4>(Aq + (size_t)bm * DFF, DFF, sA[0], tid);
  stage128<4>(B  + (size_t)bn * DFF, DFF, sB[0], tid);

  constexpr int NKT = DFF / 128;   // 64
  int c = 0;
  for (int kt = 0; kt < NKT; ++kt) {
    if (kt + 1 < NKT) {
      const int ko = (kt + 1) * 128;
      stage128<4>(Aq + (size_t)bm * DFF + ko, DFF, sA[c ^ 1], tid);
      stage128<4>(B  + (size_t)bn * DFF + ko, DFF, sB[c ^ 1], tid);
      WAIT_VMCNT(8);
    } else {
      WAIT_VMCNT(0);
    }
    hard_barrier();
    const signed char* a = sA[c];
    const signed char* b = sB[c];
#pragma unroll
    for (int s = 0; s < 2; ++s) {
      i32x4 af[8], bf[4];
#pragma unroll
      for (int i = 0; i < 8; ++i) af[i] = lds_frag(a, wm + i * 16 + fr, s, fq);
#pragma unroll
      for (int j = 0; j < 4; ++j) bf[j] = lds_frag(b, wn + j * 16 + fr, s, fq);
      __builtin_amdgcn_s_setprio(1);
#pragma unroll
      for (int i = 0; i < 8; ++i)
#pragma unroll
        for (int j = 0; j < 4; ++j)
          acc[i][j] = __builtin_amdgcn_mfma_i32_16x16x64_i8(af[i], bf[j], acc[i][j], 0, 0, 0);
      __builtin_amdgcn_s_setprio(0);
    }
    hard_barrier();
    c ^= 1;
  }

  const float sw = 1.0f / fmaxf(wsum2[0] * (1.0f / 16777216.0f), QEPS);
#pragma unroll
  for (int i = 0; i < 8; ++i) {
#pragma unroll
    for (int r = 0; r < 4; ++r) {
      const int m = bm + wm + i * 16 + fq * 4 + r;
      const float id = 0.5f / (s_a[m] * sw);      // one div per row
#pragma unroll
      for (int j = 0; j < 4; ++j)
        C[(size_t)m * EMB + (bn + wn + j * 16 + fr)] = (float)acc[i][j][r] * id;
    }
  }
}

extern "C" void kernel_launch(void* const* d_in, const int* in_sizes, int n_in,
                              void* d_out, int out_size, void* d_ws, size_t ws_size,
                              hipStream_t stream) {
  const float* x  = (const float*)d_in[0];
  const float* w1 = (const float*)d_in[1];
  const float* w2 = (const float*)d_in[2];
  const float* w3 = (const float*)d_in[3];
  float* out = (float*)d_out;

  const size_t NW = (size_t)DFF * EMB;       // 2^24 elems per weight
  const size_t MB = 1ull << 20;

  char* ws = (char*)d_ws;
  float* wsum = (float*)ws;                  // 3 accurate fp32 sums
  float* s_x  = (float*)(ws + 4096);         // 8192 floats
  float* s_h  = (float*)(ws + 4096 + 32768); // 8192 floats
  float* parts = (float*)(ws + 128 * 1024);  // 3 x 512 floats
  signed char* xq  = (signed char*)(ws + MB);
  signed char* wq1 = (signed char*)(ws + 33 * MB);
  signed char* wq3 = wq1;                    // overlay (wq1 dead after dual GEMM)
  signed char* wq2 = (signed char*)(ws + 65 * MB);
  signed char* hq  = (signed char*)(ws + 97 * MB);
  float* H = (float*)d_out;                  // fp32 H chunk buffer

  np_absmean_stage1<<<512, 256, 0, stream>>>(w1, parts);
  np_absmean_stage2<<<1, 256, 0, stream>>>(parts, wsum + 0);
  np_absmean_stage1<<<512, 256, 0, stream>>>(w2, parts + 512);
  np_absmean_stage2<<<1, 256, 0, stream>>>(parts + 512, wsum + 1);
  np_absmean_stage1<<<512, 256, 0, stream>>>(w3, parts + 1024);
  np_absmean_stage2<<<1, 256, 0, stream>>>(parts + 1024, wsum + 2);
  quant_w_kernel<<<1024, 256, 0, stream>>>(w1, wq1, wsum + 0, NW / 4);
  quant_w_kernel<<<1024, 256, 0, stream>>>(w2, wq2, wsum + 1, NW / 4);
  rms_quant_x_kernel<<<MTOK, 256, 0, stream>>>(x, xq, s_x);

  for (int c = 0; c < MTOK / MCH; ++c) {
    dual_gemm_silu_kernel<<<dim3(DFF / 128, MCH / 128), 256, 0, stream>>>(
        xq + (size_t)c * MCH * EMB, wq1, wq2, H, s_x + c * MCH, wsum);
    rms_quant_h_kernel<<<MCH, 256, 0, stream>>>(
        H, hq + (size_t)c * MCH * DFF, s_h + c * MCH);
  }

  quant_w_kernel<<<1024, 256, 0, stream>>>(w3, wq3, wsum + 2, NW / 4);
  gemm_out_kernel<<<dim3(EMB / 256, MTOK / 256), 512, 0, stream>>>(
      hq, wq3, out, s_h, wsum + 2);
}

// Round 12
// 749.877 us; speedup vs baseline: 1.2313x; 1.0725x over previous
//
#include <hip/hip_runtime.h>
#include <cstdint>
#include <cstddef>

#define DEV __device__ __forceinline__

static constexpr float QEPS = 1e-5f;   // reference EPS
static constexpr int   MTOK = 8192;    // B*S tokens
static constexpr int   EMB  = 2048;    // N_EMBD
static constexpr int   DFF  = 8192;    // 4*N_EMBD
static constexpr int   MCH  = 2048;    // M-chunk rows for fp32-H staging in d_out

typedef __attribute__((ext_vector_type(4))) int   i32x4;

// async 16B global->LDS (generic -> AS1/AS3 addrspace casts).
DEV void async_cp16(const void* g, void* l) {
  __builtin_amdgcn_global_load_lds(
      (const __attribute__((address_space(1))) void*)g,
      (__attribute__((address_space(3))) void*)l, 16, 0, 0);
}

// Raw barrier with compiler + machine-scheduler fences on both sides
// (gemm_out deep pipeline only; __syncthreads would drain vmcnt to 0).
DEV void hard_barrier() {
  __builtin_amdgcn_sched_barrier(0);
  asm volatile("" ::: "memory");
  __builtin_amdgcn_s_barrier();
  asm volatile("" ::: "memory");
  __builtin_amdgcn_sched_barrier(0);
}

#define WAIT_VMCNT(N) do {                                   \
  __builtin_amdgcn_sched_barrier(0);                         \
  asm volatile("s_waitcnt vmcnt(" #N ")" ::: "memory");      \
  __builtin_amdgcn_sched_barrier(0);                         \
} while (0)

// ---- 512-thread staging: (PASSES*64) rows x 128B, 8-chunk XOR swizzle -------
// physical 16B chunk p of row r holds logical p ^ (r&7); dest linear
// (gload_lds HW rule: wave base + lane*16), swizzle on per-lane global source.
template<int PASSES>
DEV void stage128(const signed char* __restrict__ g, size_t ldb,
                  signed char* lds, int tid) {
  const int w  = tid >> 6, l = tid & 63;
  const int r8 = l >> 3;
  const int p  = l & 7;
  const int q  = p ^ r8;
#pragma unroll
  for (int it = 0; it < PASSES; ++it) {
    const int row = it * 64 + w * 8 + r8;
    async_cp16(g + (size_t)row * ldb + q * 16, lds + row * 128 + p * 16);
  }
}

// ---- 256-thread staging: (PASSES*32) rows x 128B, same 8-chunk XOR swizzle --
template<int PASSES>
DEV void stage128_t256(const signed char* __restrict__ g, size_t ldb,
                       signed char* lds, int tid) {
  const int w  = tid >> 6, l = tid & 63;   // 4 waves
  const int r8 = l >> 3;
  const int p  = l & 7;
  const int q  = p ^ r8;
#pragma unroll
  for (int it = 0; it < PASSES; ++it) {
    const int row = it * 32 + w * 8 + r8;
    async_cp16(g + (size_t)row * ldb + q * 16, lds + row * 128 + p * 16);
  }
}

// Swizzled fragment read for the 128B-row layout: K-slice s, 16B chunk fq.
DEV i32x4 lds_frag(const signed char* lds, int row, int s, int fq) {
  const int ch = ((s * 4 + fq) ^ (row & 7)) * 16;
  return *(const i32x4*)&lds[row * 128 + ch];
}

DEV float block_sum(float v) {
#pragma unroll
  for (int off = 32; off > 0; off >>= 1) v += __shfl_down(v, off);
  __shared__ float b[4];
  if ((threadIdx.x & 63) == 0) b[threadIdx.x >> 6] = v;
  __syncthreads();
  return (b[0] + b[1]) + (b[2] + b[3]);
}

DEV float block_max(float v) {
#pragma unroll
  for (int off = 32; off > 0; off >>= 1) v = fmaxf(v, __shfl_down(v, off));
  __shared__ float b[4];
  if ((threadIdx.x & 63) == 0) b[threadIdx.x >> 6] = v;
  __syncthreads();
  return fmaxf(fmaxf(b[0], b[1]), fmaxf(b[2], b[3]));
}

// ---------------- accurate fp32 pairwise-style sum of |w|, n = 2^24 ----------
__global__ __launch_bounds__(256) void np_absmean_stage1(
    const float* __restrict__ w, float* __restrict__ partials) {
  const int t = threadIdx.x;
  const size_t leaf = (size_t)blockIdx.x * 256 + t;
  const float4* a4 = (const float4*)(w + leaf * 128);
  float L[16];
#pragma unroll
  for (int q = 0; q < 4; ++q) {
    float4 v0 = a4[q +  0];
    float4 v1 = a4[q +  4];
    float4 v2 = a4[q +  8];
    float4 v3 = a4[q + 12];
    float4 v4 = a4[q + 16];
    float4 v5 = a4[q + 20];
    float4 v6 = a4[q + 24];
    float4 v7 = a4[q + 28];
    L[4*q+0] = ((fabsf(v0.x)+fabsf(v1.x)) + (fabsf(v2.x)+fabsf(v3.x)))
             + ((fabsf(v4.x)+fabsf(v5.x)) + (fabsf(v6.x)+fabsf(v7.x)));
    L[4*q+1] = ((fabsf(v0.y)+fabsf(v1.y)) + (fabsf(v2.y)+fabsf(v3.y)))
             + ((fabsf(v4.y)+fabsf(v5.y)) + (fabsf(v6.y)+fabsf(v7.y)));
    L[4*q+2] = ((fabsf(v0.z)+fabsf(v1.z)) + (fabsf(v2.z)+fabsf(v3.z)))
             + ((fabsf(v4.z)+fabsf(v5.z)) + (fabsf(v6.z)+fabsf(v7.z)));
    L[4*q+3] = ((fabsf(v0.w)+fabsf(v1.w)) + (fabsf(v2.w)+fabsf(v3.w)))
             + ((fabsf(v4.w)+fabsf(v5.w)) + (fabsf(v6.w)+fabsf(v7.w)));
  }
#pragma unroll
  for (int l = 0; l < 8; ++l) L[l] += L[l + 8];
#pragma unroll
  for (int l = 0; l < 4; ++l) L[l] += L[l + 4];
  L[0] += L[2]; L[1] += L[3];
  const float res = L[0] + L[1];

  __shared__ float s[256];
  s[t] = res;
  __syncthreads();
  for (int width = 256; width > 1; width >>= 1) {
    const int half = width >> 1;
    float v = 0.f;
    if (t < half) v = s[2 * t] + s[2 * t + 1];
    __syncthreads();
    if (t < half) s[t] = v;
    __syncthreads();
  }
  if (t == 0) partials[blockIdx.x] = s[0];
}

__global__ __launch_bounds__(256) void np_absmean_stage2(
    const float* __restrict__ partials, float* __restrict__ out) {
  const int t = threadIdx.x;
  __shared__ float s[512];
  s[t] = partials[t];
  s[t + 256] = partials[t + 256];
  __syncthreads();
  for (int width = 512; width > 1; width >>= 1) {
    const int half = width >> 1;
    float v = 0.f;
    if (t < half) v = s[2 * t] + s[2 * t + 1];
    __syncthreads();
    if (t < half) s[t] = v;
    __syncthreads();
  }
  if (t == 0) out[0] = s[0];
}

// ---------------- ternary weight quant w/ boundary hedge -> int8 {0,±1,±2} ---
__global__ __launch_bounds__(256) void quant_w_kernel(
    const float* __restrict__ w, signed char* __restrict__ wq,
    const float* __restrict__ sumf, size_t n4) {
  const double mean = (double)(*sumf) * (1.0 / 16777216.0);   // /2^24 exact
  const double sc   = 1.0 / fmax(mean, (double)QEPS);
  const float4* w4 = (const float4*)w;
  int* o4 = (int*)wq;
  const size_t stride = (size_t)gridDim.x * blockDim.x;
  for (size_t i = (size_t)blockIdx.x * blockDim.x + threadIdx.x; i < n4; i += stride) {
    float4 v = w4[i];
    union { int i4; signed char c[4]; } p;
#pragma unroll
    for (int j = 0; j < 4; ++j) {
      const double pd = (double)(&v.x)[j] * sc;
      double r = fmin(fmax(rint(pd), -1.0), 1.0);
      if (fabs(fabs(pd) - 0.5) < 2e-7) r = (pd > 0.0) ? 0.5 : -0.5;
      p.c[j] = (signed char)(int)(2.0 * r);
    }
    o4[i] = p.i4;
  }
}

// ---------------- rmsnorm + absmax-quant of x rows (2048) -> int8 + scale ----
__global__ __launch_bounds__(256) void rms_quant_x_kernel(
    const float* __restrict__ x, signed char* __restrict__ xq,
    float* __restrict__ s_out) {
  const size_t row = blockIdx.x;
  const float* xr = x + row * EMB;
  const int t = threadIdx.x;
  float4 v0 = ((const float4*)xr)[t];
  float4 v1 = ((const float4*)xr)[t + 256];
  float vals[8] = {v0.x, v0.y, v0.z, v0.w, v1.x, v1.y, v1.z, v1.w};
  float ss = 0.f;
#pragma unroll
  for (int i = 0; i < 8; ++i) ss += vals[i] * vals[i];
  ss = block_sum(ss);
  const float r = 1.0f / sqrtf(ss * (1.0f / (float)EMB) + 1e-6f);
  float xn[8], am = 0.f;
#pragma unroll
  for (int i = 0; i < 8; ++i) { xn[i] = vals[i] * r; am = fmaxf(am, fabsf(xn[i])); }
  am = block_max(am);
  const float s = 127.0f / fmaxf(am, QEPS);
  union { int i; signed char c[4]; } p0, p1;
#pragma unroll
  for (int i = 0; i < 4; ++i) {
    p0.c[i] = (signed char)(int)fminf(fmaxf(rintf(xn[i]     * s), -128.f), 127.f);
    p1.c[i] = (signed char)(int)fminf(fmaxf(rintf(xn[4 + i] * s), -128.f), 127.f);
  }
  int* qr = (int*)(xq + row * EMB);
  qr[t]       = p0.i;
  qr[t + 256] = p1.i;
  if (t == 0) s_out[row] = s;
}

// ---------------- rmsnorm + absmax-quant of fp32 H rows (8192) -> int8 + scale
__global__ __launch_bounds__(256) void rms_quant_h_kernel(
    const float* __restrict__ H, signed char* __restrict__ hq,
    float* __restrict__ s_out) {
  const size_t row = blockIdx.x;
  const float* hr = H + row * (size_t)DFF;
  const int t = threadIdx.x;
  float vals[32];
#pragma unroll
  for (int k = 0; k < 8; ++k) {
    float4 v = ((const float4*)hr)[t + k * 256];
    vals[k * 4 + 0] = v.x; vals[k * 4 + 1] = v.y;
    vals[k * 4 + 2] = v.z; vals[k * 4 + 3] = v.w;
  }
  float ss = 0.f;
#pragma unroll
  for (int i = 0; i < 32; ++i) ss += vals[i] * vals[i];
  ss = block_sum(ss);
  const float r = 1.0f / sqrtf(ss * (1.0f / (float)DFF) + 1e-6f);
  float am = 0.f;
#pragma unroll
  for (int i = 0; i < 32; ++i) { vals[i] *= r; am = fmaxf(am, fabsf(vals[i])); }
  am = block_max(am);
  const float s = 127.0f / fmaxf(am, QEPS);
  int* qrow = (int*)(hq + row * (size_t)DFF);
#pragma unroll
  for (int k = 0; k < 8; ++k) {
    union { int i; signed char c[4]; } p;
#pragma unroll
    for (int j = 0; j < 4; ++j) {
      float q = fminf(fmaxf(rintf(vals[k * 4 + j] * s), -128.f), 127.f);
      p.c[j] = (signed char)(int)q;
    }
    qrow[t + k * 256] = p.i;
  }
  if (t == 0) s_out[row] = s;
}

// ---------------- dual GEMM i8, 128x128 tile, BK=128, 2 blocks/CU ------------
// 16 iterations (half the barrier-drain stalls of BK=64), 64 MFMA per barrier,
// single-buffered (LDS 3x16K = 48K -> 2 blocks/CU for cross-block overlap),
// fast epilogue (per-row folded reciprocal + native exp/rcp silu).
__global__ __launch_bounds__(256, 2) void dual_gemm_silu_kernel(
    const signed char* __restrict__ Xq, const signed char* __restrict__ W1,
    const signed char* __restrict__ W2, float* __restrict__ H,
    const float* __restrict__ s_x, const float* __restrict__ wsum) {
  __shared__ alignas(16) signed char sA [128 * 128];
  __shared__ alignas(16) signed char sB1[128 * 128];
  __shared__ alignas(16) signed char sB2[128 * 128];
  const int tid = threadIdx.x;
  const int lane = tid & 63, wv = tid >> 6;
  const int wm = (wv >> 1) * 64, wn = (wv & 1) * 64;
  const int bm = blockIdx.y * 128, bn = blockIdx.x * 128;
  const int fr = lane & 15, fq = lane >> 4;

  i32x4 acc1[4][4] = {}, acc2[4][4] = {};

  for (int k0 = 0; k0 < EMB; k0 += 128) {
    stage128_t256<4>(Xq + (size_t)bm * EMB + k0, EMB, sA,  tid);
    stage128_t256<4>(W1 + (size_t)bn * EMB + k0, EMB, sB1, tid);
    stage128_t256<4>(W2 + (size_t)bn * EMB + k0, EMB, sB2, tid);
    __syncthreads();          // drains vmcnt(0): all 12 loads landed
#pragma unroll
    for (int s = 0; s < 2; ++s) {
      i32x4 af[4], f1[4], f2[4];
#pragma unroll
      for (int i = 0; i < 4; ++i) af[i] = lds_frag(sA,  wm + i * 16 + fr, s, fq);
#pragma unroll
      for (int j = 0; j < 4; ++j) {
        f1[j] = lds_frag(sB1, wn + j * 16 + fr, s, fq);
        f2[j] = lds_frag(sB2, wn + j * 16 + fr, s, fq);
      }
#pragma unroll
      for (int i = 0; i < 4; ++i)
#pragma unroll
        for (int j = 0; j < 4; ++j) {
          acc1[i][j] = __builtin_amdgcn_mfma_i32_16x16x64_i8(af[i], f1[j], acc1[i][j], 0, 0, 0);
          acc2[i][j] = __builtin_amdgcn_mfma_i32_16x16x64_i8(af[i], f2[j], acc2[i][j], 0, 0, 0);
        }
    }
    __syncthreads();          // all waves done reading before next stage
  }

  const float sw1 = 1.0f / fmaxf(wsum[0] * (1.0f / 16777216.0f), QEPS);
  const float sw2 = 1.0f / fmaxf(wsum[1] * (1.0f / 16777216.0f), QEPS);
#pragma unroll
  for (int i = 0; i < 4; ++i) {
#pragma unroll
    for (int r = 0; r < 4; ++r) {
      const int m = bm + wm + i * 16 + fq * 4 + r;
      const float id1 = 0.5f / (s_x[m] * sw1);    // one div per row
      const float id2 = 0.5f / (s_x[m] * sw2);
#pragma unroll
      for (int j = 0; j < 4; ++j) {
        const float t1 = (float)acc1[i][j][r] * id1;
        const float t2 = (float)acc2[i][j][r] * id2;
        const float sig = __builtin_amdgcn_rcpf(1.0f + __expf(-t1));
        H[(size_t)m * DFF + (bn + wn + j * 16 + fr)] = t1 * sig * t2;
      }
    }
  }
}

// ---------------- GEMM3 i8 (round-9 deep pipeline, fast epilogue) ------------
// 256x256 tile, BK=128, dbuf + counted vmcnt + raw barriers, 512 thr / 8 waves.
__global__ __launch_bounds__(512, 1) void gemm_out_kernel(
    const signed char* __restrict__ Aq, const signed char* __restrict__ B,
    float* __restrict__ C, const float* __restrict__ s_a,
    const float* __restrict__ wsum2) {
  __shared__ alignas(16) signed char sA[2][256 * 128];
  __shared__ alignas(16) signed char sB[2][256 * 128];
  const int tid = threadIdx.x;
  const int lane = tid & 63, wv = tid >> 6;
  const int wm = (wv >> 2) * 128, wn = (wv & 3) * 64;
  // XCD swizzle: grid (8, 32) = 256 blocks, 32/XCD
  const int gx = gridDim.x;
  int lid = blockIdx.y * gx + blockIdx.x;
  const int cpx = (gx * gridDim.y) >> 3;
  lid = (lid & 7) * cpx + (lid >> 3);
  const int bm = (lid / gx) * 256, bn = (lid % gx) * 256;
  const int fr = lane & 15, fq = lane >> 4;

  i32x4 acc[8][4] = {};

  stage128<4>(Aq + (size_t)bm * DFF, DFF, sA[0], tid);
  stage128<4>(B  + (size_t)bn * DFF, DFF, sB[0], tid);

  constexpr int NKT = DFF / 128;   // 64
  int c = 0;
  for (int kt = 0; kt < NKT; ++kt) {
    if (kt + 1 < NKT) {
      const int ko = (kt + 1) * 128;
      stage128<4>(Aq + (size_t)bm * DFF + ko, DFF, sA[c ^ 1], tid);
      stage128<4>(B  + (size_t)bn * DFF + ko, DFF, sB[c ^ 1], tid);
      WAIT_VMCNT(8);
    } else {
      WAIT_VMCNT(0);
    }
    hard_barrier();
    const signed char* a = sA[c];
    const signed char* b = sB[c];
#pragma unroll
    for (int s = 0; s < 2; ++s) {
      i32x4 af[8], bf[4];
#pragma unroll
      for (int i = 0; i < 8; ++i) af[i] = lds_frag(a, wm + i * 16 + fr, s, fq);
#pragma unroll
      for (int j = 0; j < 4; ++j) bf[j] = lds_frag(b, wn + j * 16 + fr, s, fq);
      __builtin_amdgcn_s_setprio(1);
#pragma unroll
      for (int i = 0; i < 8; ++i)
#pragma unroll
        for (int j = 0; j < 4; ++j)
          acc[i][j] = __builtin_amdgcn_mfma_i32_16x16x64_i8(af[i], bf[j], acc[i][j], 0, 0, 0);
      __builtin_amdgcn_s_setprio(0);
    }
    hard_barrier();
    c ^= 1;
  }

  const float sw = 1.0f / fmaxf(wsum2[0] * (1.0f / 16777216.0f), QEPS);
#pragma unroll
  for (int i = 0; i < 8; ++i) {
#pragma unroll
    for (int r = 0; r < 4; ++r) {
      const int m = bm + wm + i * 16 + fq * 4 + r;
      const float id = 0.5f / (s_a[m] * sw);      // one div per row
#pragma unroll
      for (int j = 0; j < 4; ++j)
        C[(size_t)m * EMB + (bn + wn + j * 16 + fr)] = (float)acc[i][j][r] * id;
    }
  }
}

extern "C" void kernel_launch(void* const* d_in, const int* in_sizes, int n_in,
                              void* d_out, int out_size, void* d_ws, size_t ws_size,
                              hipStream_t stream) {
  const float* x  = (const float*)d_in[0];
  const float* w1 = (const float*)d_in[1];
  const float* w2 = (const float*)d_in[2];
  const float* w3 = (const float*)d_in[3];
  float* out = (float*)d_out;

  const size_t NW = (size_t)DFF * EMB;       // 2^24 elems per weight
  const size_t MB = 1ull << 20;

  char* ws = (char*)d_ws;
  float* wsum = (float*)ws;                  // 3 accurate fp32 sums
  float* s_x  = (float*)(ws + 4096);         // 8192 floats
  float* s_h  = (float*)(ws + 4096 + 32768); // 8192 floats
  float* parts = (float*)(ws + 128 * 1024);  // 3 x 512 floats
  signed char* xq  = (signed char*)(ws + MB);
  signed char* wq1 = (signed char*)(ws + 33 * MB);
  signed char* wq3 = wq1;                    // overlay (wq1 dead after dual GEMM)
  signed char* wq2 = (signed char*)(ws + 65 * MB);
  signed char* hq  = (signed char*)(ws + 97 * MB);
  float* H = (float*)d_out;                  // fp32 H chunk buffer

  np_absmean_stage1<<<512, 256, 0, stream>>>(w1, parts);
  np_absmean_stage2<<<1, 256, 0, stream>>>(parts, wsum + 0);
  np_absmean_stage1<<<512, 256, 0, stream>>>(w2, parts + 512);
  np_absmean_stage2<<<1, 256, 0, stream>>>(parts + 512, wsum + 1);
  np_absmean_stage1<<<512, 256, 0, stream>>>(w3, parts + 1024);
  np_absmean_stage2<<<1, 256, 0, stream>>>(parts + 1024, wsum + 2);
  quant_w_kernel<<<1024, 256, 0, stream>>>(w1, wq1, wsum + 0, NW / 4);
  quant_w_kernel<<<1024, 256, 0, stream>>>(w2, wq2, wsum + 1, NW / 4);
  rms_quant_x_kernel<<<MTOK, 256, 0, stream>>>(x, xq, s_x);

  for (int c = 0; c < MTOK / MCH; ++c) {
    dual_gemm_silu_kernel<<<dim3(DFF / 128, MCH / 128), 256, 0, stream>>>(
        xq + (size_t)c * MCH * EMB, wq1, wq2, H, s_x + c * MCH, wsum);
    rms_quant_h_kernel<<<MCH, 256, 0, stream>>>(
        H, hq + (size_t)c * MCH * DFF, s_h + c * MCH);
  }

  quant_w_kernel<<<1024, 256, 0, stream>>>(w3, wq3, wsum + 2, NW / 4);
  gemm_out_kernel<<<dim3(EMB / 256, MTOK / 256), 512, 0, stream>>>(
      hq, wq3, out, s_h, wsum + 2);
}